// Round 1
// baseline (1420.473 us; speedup 1.0000x reference)
//
#include <hip/hip_runtime.h>
#include <math.h>

// ---- problem constants ----
#define LL   4
#define BB   3
#define DD   2048
#define HH   16
#define HDD  128
#define KVH  2
#define FF   6144
#define VV   32000
#define TP   4095
#define TT   4096
#define NSP  32
#define EPSF 1e-6f
#define QKSCALE 0.29730177875068026f   // 128^-0.25

// ---- workspace layout (float offsets) ----
#define WS_H      0        // [3][2048] hidden state
#define WS_HN     6144     // [3][2048] normed
#define WS_QRAW   12288    // [3][2048]  (zeroed region start)
#define WS_KRAW   18432    // [3][256]
#define WS_VRAW   19200    // [3][256]
#define WS_GACC   19968    // [3][6144]
#define WS_UACC   38400    // [3][6144]  (zeroed region end: 56832)
#define WS_Q      56832    // [3][16][128] roped q
#define WS_NEWK   62976    // [3][2][128]
#define WS_NEWV   63744    // [3][2][128]
#define WS_PART   64512    // [6][32][1040] flash-decode partials
#define WS_ATTNO  264192   // [3][2048]
#define WS_LAST   270336   // [3][2048]

// =============== rmsnorm over D=2048, one block per batch row ===============
__global__ void rmsnorm_k(const float* __restrict__ x, const float* __restrict__ w,
                          float* __restrict__ out) {
  int b = blockIdx.x;
  const float* xb = x + b * DD;
  float ss = 0.f;
  for (int d = threadIdx.x; d < DD; d += 256) { float v = xb[d]; ss += v * v; }
  for (int off = 32; off; off >>= 1) ss += __shfl_down(ss, off);
  __shared__ float red[4];
  if ((threadIdx.x & 63) == 0) red[threadIdx.x >> 6] = ss;
  __syncthreads();
  float tot = red[0] + red[1] + red[2] + red[3];
  float r = rsqrtf(tot / (float)DD + EPSF);
  float* ob = out + b * DD;
  for (int d = threadIdx.x; d < DD; d += 256) ob[d] = xb[d] * r * w[d];
}

// =============== generic k-split GEMV, atomic accumulate ===============
// x: [3][K] (ignored if gp!=null: x = silu(gp)*up on the fly)
// W: [K][N] row-major; out: [3][N] atomicAdd
// grid: (col_tiles, ksplit); block 256; 2 cols/thread
__global__ void gemv_k(const float* __restrict__ x, const float* __restrict__ W,
                       float* __restrict__ out, int K, int N, int kchunk,
                       const float* __restrict__ gp, const float* __restrict__ up,
                       const float* __restrict__ ds) {
  __shared__ float xs[3 * 512];
  int d0 = blockIdx.y * kchunk;
  for (int idx = threadIdx.x; idx < 3 * kchunk; idx += 256) {
    int b = idx / kchunk, dl = idx - b * kchunk;
    int d = d0 + dl;
    float v;
    if (gp) { float g = gp[b * K + d]; float u = up[b * K + d];
              v = g / (1.f + __expf(-g)) * u; }
    else v = x[b * K + d];
    xs[idx] = v;
  }
  __syncthreads();
  int col = (blockIdx.x * 256 + threadIdx.x) * 2;
  if (col >= N) return;
  float a00 = 0, a01 = 0, a10 = 0, a11 = 0, a20 = 0, a21 = 0;
  const float* Wp = W + (size_t)d0 * N + col;
  const float* x0 = xs, * x1 = xs + kchunk, * x2 = xs + 2 * kchunk;
  for (int dl = 0; dl < kchunk; ++dl) {
    float2 w2 = *(const float2*)Wp;
    float b0 = x0[dl], b1 = x1[dl], b2 = x2[dl];
    a00 += b0 * w2.x; a01 += b0 * w2.y;
    a10 += b1 * w2.x; a11 += b1 * w2.y;
    a20 += b2 * w2.x; a21 += b2 * w2.y;
    Wp += N;
  }
  if (ds && blockIdx.y == 0) {
    a00 += ds[col];          a01 += ds[col + 1];
    a10 += ds[N + col];      a11 += ds[N + col + 1];
    a20 += ds[2 * N + col];  a21 += ds[2 * N + col + 1];
  }
  atomicAdd(&out[col], a00);          atomicAdd(&out[col + 1], a01);
  atomicAdd(&out[N + col], a10);      atomicAdd(&out[N + col + 1], a11);
  atomicAdd(&out[2 * N + col], a20);  atomicAdd(&out[2 * N + col + 1], a21);
}

// =============== q/k rmsnorm + RoPE, v passthrough; write new kv to outputs ===============
// grid: 3*(16+2) blocks, 128 threads. oks/ovs are layer-base pointers into d_out.
__global__ void qkrope_k(const float* __restrict__ qraw, const float* __restrict__ kraw,
                         const float* __restrict__ vraw, const float* __restrict__ wqn,
                         const float* __restrict__ wkn, const float* __restrict__ cq,
                         const float* __restrict__ sq, float* __restrict__ qout,
                         float* __restrict__ newk, float* __restrict__ newv,
                         float* __restrict__ oks, float* __restrict__ ovs) {
  int bx = blockIdx.x;
  int b = bx / 18, u = bx - b * 18;
  int j = threadIdx.x;
  __shared__ float xn[128];
  __shared__ float red[2];
  if (u < HH) {
    float x = qraw[b * 2048 + u * 128 + j];
    float ss = x * x;
    for (int off = 32; off; off >>= 1) ss += __shfl_down(ss, off);
    if ((j & 63) == 0) red[j >> 6] = ss;
    __syncthreads();
    float r = rsqrtf((red[0] + red[1]) / 128.f + EPSF);
    float v = x * r * (wqn[j] * QKSCALE);
    xn[j] = v;
    __syncthreads();
    float p = (j < 64) ? -xn[j + 64] : xn[j - 64];
    qout[b * 2048 + u * 128 + j] = v * cq[j] + p * sq[j];
  } else {
    int c = u - 16;
    float x = kraw[b * 256 + c * 128 + j];
    float ss = x * x;
    for (int off = 32; off; off >>= 1) ss += __shfl_down(ss, off);
    if ((j & 63) == 0) red[j >> 6] = ss;
    __syncthreads();
    float r = rsqrtf((red[0] + red[1]) / 128.f + EPSF);
    float v = x * r * (wkn[j] * QKSCALE);
    xn[j] = v;
    __syncthreads();
    float p = (j < 64) ? -xn[j + 64] : xn[j - 64];
    float ko = v * cq[j] + p * sq[j];
    newk[(b * 2 + c) * 128 + j] = ko;
    oks[(size_t)(b * 2 + c) * 524288 + (size_t)j * 4096 + 4095] = ko;
    float vv = vraw[b * 256 + c * 128 + j];
    newv[(b * 2 + c) * 128 + j] = vv;
    ovs[(size_t)(b * 2 + c) * 524288 + 4095 * 128 + j] = vv;
  }
}

// =============== flash-decode attention: partial pass ===============
// grid: 3*2*32 blocks, 256 threads; each block = (b, kv-head, T-split of 128)
__global__ void attn_part_k(const float* __restrict__ q,
                            const float* __restrict__ Kpast,  // layer base [B][KVH][128][4095]
                            const float* __restrict__ Vpast,  // layer base [B][KVH][4095][128]
                            const float* __restrict__ newk, const float* __restrict__ newv,
                            const float* __restrict__ ascale,
                            float* __restrict__ part) {
  int bx = blockIdx.x;
  int split = bx & 31, kv = (bx >> 5) & 1, b = bx >> 6;
  int tid = threadIdx.x;
  __shared__ float qs[8][128];
  __shared__ float sc[8][128];
  __shared__ float sm[8], sl[8];
  for (int idx = tid; idx < 1024; idx += 256) {
    int g = idx >> 7, j = idx & 127;
    qs[g][j] = q[b * 2048 + (kv * 8 + g) * 128 + j];
  }
  __syncthreads();
  int tl = tid & 127, gg = tid >> 7;
  int t = split * 128 + tl;
  const float* Kb = Kpast + (size_t)(b * 2 + kv) * 524160;
  const float* nkb = newk + (b * 2 + kv) * 128;
  int tt = t < TP ? t : (TP - 1);
  bool isnew = (t == TP);
  float acc0 = 0, acc1 = 0, acc2 = 0, acc3 = 0;
  #pragma unroll 4
  for (int hd = 0; hd < 128; ++hd) {
    float kvv = isnew ? nkb[hd] : Kb[(size_t)hd * 4095 + tt];
    acc0 += kvv * qs[gg * 4 + 0][hd];
    acc1 += kvv * qs[gg * 4 + 1][hd];
    acc2 += kvv * qs[gg * 4 + 2][hd];
    acc3 += kvv * qs[gg * 4 + 3][hd];
  }
  float a = ascale[0];
  float maskv = (t > 0) ? (-128.f * a) : 0.f;
  sc[gg * 4 + 0][tl] = acc0 + maskv;
  sc[gg * 4 + 1][tl] = acc1 + maskv;
  sc[gg * 4 + 2][tl] = acc2 + maskv;
  sc[gg * 4 + 3][tl] = acc3 + maskv;
  __syncthreads();
  { // chunk-local softmax, one 32-thread group per head
    int g = tid >> 5, sub = tid & 31;
    float mm = -3.0e38f;
    for (int x = sub; x < 128; x += 32) mm = fmaxf(mm, sc[g][x]);
    for (int off = 16; off; off >>= 1) mm = fmaxf(mm, __shfl_down(mm, off, 32));
    mm = __shfl(mm, 0, 32);
    float ll = 0.f;
    for (int x = sub; x < 128; x += 32) {
      float p = __expf(sc[g][x] - mm);
      sc[g][x] = p; ll += p;
    }
    for (int off = 16; off; off >>= 1) ll += __shfl_down(ll, off, 32);
    if (sub == 0) { sm[g] = mm; sl[g] = ll; }
  }
  __syncthreads();
  int hd = tid & 127;
  const float* Vb = Vpast + (size_t)(b * 2 + kv) * 524160;
  const float* nvb = newv + (b * 2 + kv) * 128;
  float o0 = 0, o1 = 0, o2 = 0, o3 = 0;
  for (int x = 0; x < 128; ++x) {
    int t2 = split * 128 + x;
    float vv = (t2 == TP) ? nvb[hd] : Vb[(size_t)(t2 < TP ? t2 : TP - 1) * 128 + hd];
    o0 += sc[gg * 4 + 0][x] * vv;
    o1 += sc[gg * 4 + 1][x] * vv;
    o2 += sc[gg * 4 + 2][x] * vv;
    o3 += sc[gg * 4 + 3][x] * vv;
  }
  size_t pb = (size_t)((b * 2 + kv) * 32 + split) * 1040;
  part[pb + 16 + (gg * 4 + 0) * 128 + hd] = o0;
  part[pb + 16 + (gg * 4 + 1) * 128 + hd] = o1;
  part[pb + 16 + (gg * 4 + 2) * 128 + hd] = o2;
  part[pb + 16 + (gg * 4 + 3) * 128 + hd] = o3;
  if (tid < 8) { part[pb + tid] = sm[tid]; part[pb + 8 + tid] = sl[tid]; }
}

// =============== flash-decode combine: 6 blocks ===============
__global__ void attn_comb_k(const float* __restrict__ part, float* __restrict__ attn_out) {
  int bx = blockIdx.x;
  int kv = bx & 1, b = bx >> 1;
  int tid = threadIdx.x;
  __shared__ float ew[32][8];
  __shared__ float Lg[8];
  size_t pb = (size_t)(b * 2 + kv) * 32 * 1040;
  if (tid < 8) {
    int g = tid;
    float M = -3.0e38f;
    for (int s = 0; s < 32; ++s) M = fmaxf(M, part[pb + s * 1040 + g]);
    float Ltot = 0.f;
    for (int s = 0; s < 32; ++s) {
      float e = __expf(part[pb + s * 1040 + g] - M);
      ew[s][g] = e;
      Ltot += e * part[pb + s * 1040 + 8 + g];
    }
    Lg[g] = Ltot;
  }
  __syncthreads();
  int hd = tid & 127, gg = tid >> 7;
  for (int r = 0; r < 4; ++r) {
    int g = gg * 4 + r;
    float acc = 0.f;
    for (int s = 0; s < 32; ++s)
      acc += ew[s][g] * part[pb + s * 1040 + 16 + g * 128 + hd];
    attn_out[b * 2048 + (kv * 8 + g) * 128 + hd] = acc / Lg[g];
  }
}

// =============== KV cache copy into outputs (t < 4095 part) ===============
__global__ void copy_k_cache(const float* __restrict__ pk, float* __restrict__ oks) {
  int idx = blockIdx.x * 256 + threadIdx.x;   // over 24*128*4096
  int t = idx & 4095;
  if (t >= TP) return;
  int hd = (idx >> 12) & 127;
  int rc = idx >> 19;
  oks[idx] = pk[(size_t)rc * 524160 + (size_t)hd * 4095 + t];
}

__global__ void copy_v_cache(const float* __restrict__ pv, float* __restrict__ ovs) {
  int rc = blockIdx.y;
  int n4 = blockIdx.x * 256 + threadIdx.x;    // float4 index within (i,b,kv) block
  if (n4 >= 131040) return;                   // 4095*128/4
  const float4* src = (const float4*)pv + (size_t)rc * 131040;
  float4* dst = (float4*)ovs + (size_t)rc * 131072;
  dst[n4] = src[n4];
}

extern "C" void kernel_launch(void* const* d_in, const int* in_sizes, int n_in,
                              void* d_out, int out_size, void* d_ws, size_t ws_size,
                              hipStream_t stream) {
  const float* hidden   = (const float*)d_in[0];
  const float* past_k   = (const float*)d_in[1];
  const float* past_v   = (const float*)d_in[2];
  const float* deepst   = (const float*)d_in[3];
  const float* cos_q    = (const float*)d_in[4];
  const float* sin_q    = (const float*)d_in[5];
  const float* ascale   = (const float*)d_in[8];
  const float* w_in_ln  = (const float*)d_in[9];
  const float* wq       = (const float*)d_in[10];
  const float* wk       = (const float*)d_in[11];
  const float* wv       = (const float*)d_in[12];
  const float* w_qnorm  = (const float*)d_in[13];
  const float* w_knorm  = (const float*)d_in[14];
  const float* wo       = (const float*)d_in[15];
  const float* w_postln = (const float*)d_in[16];
  const float* w_gate   = (const float*)d_in[17];
  const float* w_up     = (const float*)d_in[18];
  const float* w_down   = (const float*)d_in[19];
  const float* w_fn     = (const float*)d_in[20];
  const float* w_lm     = (const float*)d_in[21];

  float* ws  = (float*)d_ws;
  float* out = (float*)d_out;
  float* oks = out + 96000;                 // [4][3][2][128][4096]
  float* ovs = oks + 12582912;              // [4][3][2][4096][128]

  // init: h = hidden_states; logits = 0; KV cache copy (independent of layers)
  hipMemcpyAsync(ws + WS_H, hidden, (size_t)BB * DD * 4, hipMemcpyDeviceToDevice, stream);
  hipMemsetAsync(out, 0, 96000 * 4, stream);
  copy_k_cache<<<49152, 256, 0, stream>>>(past_k, oks);
  copy_v_cache<<<dim3(512, 24), 256, 0, stream>>>(past_v, ovs);

  for (int i = 0; i < LL; ++i) {
    // zero atomic accumulators: qraw,kraw,vraw,g_acc,u_acc (contiguous)
    hipMemsetAsync(ws + WS_QRAW, 0, 44544 * 4, stream);
    rmsnorm_k<<<3, 256, 0, stream>>>(ws + WS_H, w_in_ln + i * DD, ws + WS_HN);
    // q/k/v projections (K=2048, kchunk=64, ksplit=32)
    gemv_k<<<dim3(4, 32), 256, 0, stream>>>(ws + WS_HN, wq + (size_t)i * DD * 2048,
                                            ws + WS_QRAW, 2048, 2048, 64, nullptr, nullptr, nullptr);
    gemv_k<<<dim3(1, 32), 256, 0, stream>>>(ws + WS_HN, wk + (size_t)i * DD * 256,
                                            ws + WS_KRAW, 2048, 256, 64, nullptr, nullptr, nullptr);
    gemv_k<<<dim3(1, 32), 256, 0, stream>>>(ws + WS_HN, wv + (size_t)i * DD * 256,
                                            ws + WS_VRAW, 2048, 256, 64, nullptr, nullptr, nullptr);
    qkrope_k<<<54, 128, 0, stream>>>(ws + WS_QRAW, ws + WS_KRAW, ws + WS_VRAW,
                                     w_qnorm + i * 128, w_knorm + i * 128, cos_q, sin_q,
                                     ws + WS_Q, ws + WS_NEWK, ws + WS_NEWV,
                                     oks + (size_t)i * 3145728, ovs + (size_t)i * 3145728);
    attn_part_k<<<192, 256, 0, stream>>>(ws + WS_Q,
                                         past_k + (size_t)i * 3144960,
                                         past_v + (size_t)i * 3144960,
                                         ws + WS_NEWK, ws + WS_NEWV, ascale, ws + WS_PART);
    attn_comb_k<<<6, 256, 0, stream>>>(ws + WS_PART, ws + WS_ATTNO);
    // out-proj + residual (atomic into h)
    gemv_k<<<dim3(4, 32), 256, 0, stream>>>(ws + WS_ATTNO, wo + (size_t)i * 2048 * 2048,
                                            ws + WS_H, 2048, 2048, 64, nullptr, nullptr, nullptr);
    rmsnorm_k<<<3, 256, 0, stream>>>(ws + WS_H, w_postln + i * DD, ws + WS_HN);
    gemv_k<<<dim3(12, 32), 256, 0, stream>>>(ws + WS_HN, w_gate + (size_t)i * DD * FF,
                                             ws + WS_GACC, 2048, 6144, 64, nullptr, nullptr, nullptr);
    gemv_k<<<dim3(12, 32), 256, 0, stream>>>(ws + WS_HN, w_up + (size_t)i * DD * FF,
                                             ws + WS_UACC, 2048, 6144, 64, nullptr, nullptr, nullptr);
    // down-proj with fused silu(g)*u input, residual via atomic, deepstack add
    gemv_k<<<dim3(4, 64), 256, 0, stream>>>(nullptr, w_down + (size_t)i * FF * DD,
                                            ws + WS_H, 6144, 2048, 96,
                                            ws + WS_GACC, ws + WS_UACC,
                                            (i < 3) ? (deepst + (size_t)i * BB * DD) : nullptr);
  }
  rmsnorm_k<<<3, 256, 0, stream>>>(ws + WS_H, w_fn, ws + WS_LAST);
  // lm_head: N=32000, K=2048, kchunk=256, ksplit=8 -> 504 blocks
  gemv_k<<<dim3(63, 8), 256, 0, stream>>>(ws + WS_LAST, w_lm, out, 2048, 32000, 256,
                                          nullptr, nullptr, nullptr);
}